// Round 1
// baseline (1945.042 us; speedup 1.0000x reference)
//
#include <hip/hip_runtime.h>
#include <math.h>

#define NN 50000
#define NE 800000
#define NG 1000
#define DN 92
#define DE 41
#define DH 128

// ws layout (floats):
//  A      [NN][128]        node state (h, then h+agg, in place)
//  P      [NN][512]        per-node gate projections (Pfi|Pfj|Psi|Psj)
//  Wcat   [2][512][128]    repacked, aligned node-side weights
//  pooled [NG][128]
#define OFF_A    0
#define OFF_P    ((size_t)NN * DH)                    // 6,400,000
#define OFF_WCAT (OFF_P + (size_t)NN * 512)           // 32,000,000
#define OFF_POOL (OFF_WCAT + (size_t)2 * 512 * 128)   // 32,131,072
// total ~32.26M floats = 129 MB

__device__ __forceinline__ float leaky(float x) { return x > 0.f ? x : 0.01f * x; }

// ---------------- K1: A = leaky_relu(x @ W_node^T + b_node) ----------------
__global__ __launch_bounds__(128) void k_node_embed(const float* __restrict__ x,
        const float* __restrict__ Wn, const float* __restrict__ bn,
        float* __restrict__ A) {
    __shared__ __align__(16) float xs[16 * DN];
    const int n0 = blockIdx.x * 16;
    const int t = threadIdx.x;
    const float4* xg = (const float4*)(x + (size_t)n0 * DN);
    float4* xs4 = (float4*)xs;
    for (int i = t; i < 16 * DN / 4; i += 128) xs4[i] = xg[i];
    __syncthreads();
    const int o = t;
    float acc[16];
#pragma unroll
    for (int n = 0; n < 16; n++) acc[n] = 0.f;
    const float4* Wr = (const float4*)(Wn + (size_t)o * DN);
    for (int kk = 0; kk < DN / 4; kk++) {
        float4 w = Wr[kk];
#pragma unroll
        for (int n = 0; n < 16; n++) {
            float4 a = ((const float4*)(xs + n * DN))[kk];
            acc[n] = fmaf(w.x, a.x, acc[n]);
            acc[n] = fmaf(w.y, a.y, acc[n]);
            acc[n] = fmaf(w.z, a.z, acc[n]);
            acc[n] = fmaf(w.w, a.w, acc[n]);
        }
    }
    float b = bn[o];
#pragma unroll
    for (int n = 0; n < 16; n++)
        A[(size_t)(n0 + n) * DH + o] = leaky(acc[n] + b);
}

// ---------------- pack Wcat[l][cb*128+o][k] = W{f,s}_l[o][cb&1 ? 128+k : k] ----
__global__ __launch_bounds__(128) void k_pack_wcat(const float* __restrict__ Wf1,
        const float* __restrict__ Ws1, const float* __restrict__ Wf2,
        const float* __restrict__ Ws2, float* __restrict__ Wcat) {
    int b = blockIdx.x;              // 0..1023 = layer*512 + row
    int l = b >> 9, row = b & 511;
    int cb = row >> 7, o = row & 127;
    const float* src;
    if (l == 0) src = (cb < 2) ? Wf1 : Ws1;
    else        src = (cb < 2) ? Wf2 : Ws2;
    int koff = (cb & 1) * 128;
    Wcat[(size_t)b * 128 + threadIdx.x] = src[(size_t)o * 297 + koff + threadIdx.x];
}

// ---------------- P = A @ Wcat^T (+bias folded into cb0/cb2) ----------------
__global__ __launch_bounds__(256) void k_gemm_P(const float* __restrict__ A,
        const float* __restrict__ Wcat, const float* __restrict__ bf,
        const float* __restrict__ bs, float* __restrict__ P) {
    __shared__ __align__(16) float As[64 * 128];
    const int n0 = blockIdx.x * 64;
    const int t = threadIdx.x;
    const float4* Ag = (const float4*)A + (size_t)n0 * 32;
    float4* As4 = (float4*)As;
    for (int i = t; i < 2048; i += 256) {
        int node = n0 + (i >> 5);
        As4[i] = (node < NN) ? Ag[i] : make_float4(0.f, 0.f, 0.f, 0.f);
    }
    __syncthreads();
    const int c = t & 127, nh = t >> 7, cb = blockIdx.y;
    const float4* Wr = (const float4*)(Wcat + ((size_t)cb * 128 + c) * 128);
    float acc[32];
#pragma unroll
    for (int n = 0; n < 32; n++) acc[n] = 0.f;
    for (int kk = 0; kk < 4; kk++) {
        float4 w[8];
#pragma unroll
        for (int jj = 0; jj < 8; jj++) w[jj] = Wr[kk * 8 + jj];
#pragma unroll
        for (int n = 0; n < 32; n++) {
            const float4* Arow = (const float4*)(As + (nh * 32 + n) * 128) + kk * 8;
#pragma unroll
            for (int jj = 0; jj < 8; jj++) {
                float4 a = Arow[jj];
                acc[n] = fmaf(w[jj].x, a.x, acc[n]);
                acc[n] = fmaf(w[jj].y, a.y, acc[n]);
                acc[n] = fmaf(w[jj].z, a.z, acc[n]);
                acc[n] = fmaf(w[jj].w, a.w, acc[n]);
            }
        }
    }
    float bias = 0.f;
    if (cb == 0) bias = bf[c];
    else if (cb == 2) bias = bs[c];
#pragma unroll
    for (int n = 0; n < 32; n++) {
        int node = n0 + nh * 32 + n;
        if (node < NN) P[(size_t)node * 512 + cb * 128 + c] = acc[n] + bias;
    }
}

// ---------------- edge kernel: msg + atomic aggregate into A ----------------
// f = Pfi[dst] + Pfj[src] + Wfe.e ; s = Psi[dst] + Psj[src] + Wse.e
// msg = sigmoid(f)*softplus(s); A[dst] += msg   (A holds h -> residual free)
__global__ __launch_bounds__(256) void k_edge(const float* __restrict__ P,
        const int* __restrict__ ei, const float* __restrict__ ea,
        const float* __restrict__ Wf, const float* __restrict__ Ws,
        float* __restrict__ A) {
    const int t = threadIdx.x;
    const int l = t & 63, wid = t >> 6;
    const int pair = wid >> 1, half = wid & 1;
    const int o = half * 64 + l;
    float wf[DE], wsr[DE];
#pragma unroll
    for (int k = 0; k < DE; k++) {
        wf[k]  = Wf[(size_t)o * 297 + 256 + k];
        wsr[k] = Ws[(size_t)o * 297 + 256 + k];
    }
    const int e0 = blockIdx.x * 64 + pair * 32;
    for (int i = 0; i < 32; i++) {
        int e = e0 + i;
        int src = ei[e], dst = ei[NE + e];
        float eval = (l < DE) ? ea[(size_t)e * DE + l] : 0.f;
        float f0 = P[(size_t)dst * 512 + o];
        float f1 = P[(size_t)src * 512 + 128 + o];
        float s0 = P[(size_t)dst * 512 + 256 + o];
        float s1 = P[(size_t)src * 512 + 384 + o];
#pragma unroll
        for (int k = 0; k < DE; k += 2) {
            float ek = __shfl(eval, k);
            f0 = fmaf(wf[k], ek, f0);
            s0 = fmaf(wsr[k], ek, s0);
            if (k + 1 < DE) {
                float ek1 = __shfl(eval, k + 1);
                f1 = fmaf(wf[k + 1], ek1, f1);
                s1 = fmaf(wsr[k + 1], ek1, s1);
            }
        }
        float f = f0 + f1, s = s0 + s1;
        float sig = 1.f / (1.f + __expf(-f));
        float sp = fmaxf(s, 0.f) + __logf(1.f + __expf(-fabsf(s)));
        atomicAdd(A + (size_t)dst * DH + o, sig * sp);
    }
}

// ---------------- elementwise leaky on A ----------------
__global__ __launch_bounds__(256) void k_act(float* __restrict__ A) {
    int i = blockIdx.x * 256 + threadIdx.x;
    float4* A4 = (float4*)A;
    float4 v = A4[i];
    v.x = leaky(v.x); v.y = leaky(v.y); v.z = leaky(v.z); v.w = leaky(v.w);
    A4[i] = v;
}

// ---------------- final activation + write atom_embs + pooling ----------------
__global__ __launch_bounds__(256) void k_finalize(const float* __restrict__ A,
        const int* __restrict__ batch, float* __restrict__ embs,
        float* __restrict__ pooled) {
    int idx = blockIdx.x * 256 + threadIdx.x;
    int n = idx >> 7, o = idx & 127;
    float v = leaky(A[idx]);
    embs[idx] = v;
    atomicAdd(pooled + (size_t)batch[n] * DH + o, v);
}

// ---------------- head: normalize, W1+leaky, W2 ----------------
__global__ __launch_bounds__(128) void k_head(const float* __restrict__ pooled,
        const float* __restrict__ W1, const float* __restrict__ b1,
        const float* __restrict__ W2, const float* __restrict__ b2,
        float* __restrict__ out) {
    __shared__ __align__(16) float gl[128];
    __shared__ float red[2];
    const int g = blockIdx.x, o = threadIdx.x;
    const int l = o & 63, wid = o >> 6;
    float p = pooled[(size_t)g * DH + o];
    float v = p * p;
#pragma unroll
    for (int off = 32; off >= 1; off >>= 1) v += __shfl_xor(v, off);
    if (l == 0) red[wid] = v;
    __syncthreads();
    float nrm = fmaxf(sqrtf(red[0] + red[1]), 1e-12f);
    float gv = p / nrm;
    gl[o] = gv;
    __syncthreads();
    float gm = b1[o];
    const float4* Wr = (const float4*)(W1 + (size_t)o * DH);
    const float4* gl4 = (const float4*)gl;
    for (int kk = 0; kk < 32; kk++) {
        float4 w = Wr[kk]; float4 a = gl4[kk];
        gm = fmaf(w.x, a.x, gm); gm = fmaf(w.y, a.y, gm);
        gm = fmaf(w.z, a.z, gm); gm = fmaf(w.w, a.w, gm);
    }
    gm = leaky(gm);
    float c = gm * W2[o];
#pragma unroll
    for (int off = 32; off >= 1; off >>= 1) c += __shfl_xor(c, off);
    __syncthreads();
    if (l == 0) red[wid] = c;
    __syncthreads();
    if (o == 0) out[g] = red[0] + red[1] + b2[0];
}

extern "C" void kernel_launch(void* const* d_in, const int* in_sizes, int n_in,
                              void* d_out, int out_size, void* d_ws, size_t ws_size,
                              hipStream_t stream) {
    const float* x    = (const float*)d_in[0];
    const int*   ei   = (const int*)d_in[1];
    const float* ea   = (const float*)d_in[2];
    const int*   batch= (const int*)d_in[3];
    const float* Wn   = (const float*)d_in[4];
    const float* bn   = (const float*)d_in[5];
    const float* Wf1  = (const float*)d_in[6];
    const float* bf1  = (const float*)d_in[7];
    const float* Ws1  = (const float*)d_in[8];
    const float* bs1  = (const float*)d_in[9];
    const float* Wf2  = (const float*)d_in[10];
    const float* bf2  = (const float*)d_in[11];
    const float* Ws2  = (const float*)d_in[12];
    const float* bs2  = (const float*)d_in[13];
    const float* W1   = (const float*)d_in[14];
    const float* b1   = (const float*)d_in[15];
    const float* W2   = (const float*)d_in[16];
    const float* b2   = (const float*)d_in[17];

    float* ws     = (float*)d_ws;
    float* A      = ws + OFF_A;
    float* P      = ws + OFF_P;
    float* Wcat   = ws + OFF_WCAT;
    float* pooled = ws + OFF_POOL;
    float* out    = (float*)d_out;
    float* embs   = out + NG;

    hipMemsetAsync(pooled, 0, (size_t)NG * DH * sizeof(float), stream);
    k_pack_wcat<<<1024, 128, 0, stream>>>(Wf1, Ws1, Wf2, Ws2, Wcat);
    k_node_embed<<<NN / 16, 128, 0, stream>>>(x, Wn, bn, A);

    // layer 1
    k_gemm_P<<<dim3(782, 4), 256, 0, stream>>>(A, Wcat, bf1, bs1, P);
    k_edge<<<NE / 64, 256, 0, stream>>>(P, ei, ea, Wf1, Ws1, A);
    k_act<<<(NN * DH / 4) / 256, 256, 0, stream>>>(A);

    // layer 2
    k_gemm_P<<<dim3(782, 4), 256, 0, stream>>>(A, Wcat + 512 * 128, bf2, bs2, P);
    k_edge<<<NE / 64, 256, 0, stream>>>(P, ei, ea, Wf2, Ws2, A);

    k_finalize<<<NN * DH / 256, 256, 0, stream>>>(A, batch, embs, pooled);
    k_head<<<NG, 128, 0, stream>>>(pooled, W1, b1, W2, b2, out);
}

// Round 2
// 1872.592 us; speedup vs baseline: 1.0387x; 1.0387x over previous
//
#include <hip/hip_runtime.h>
#include <math.h>

#define NN 50000
#define NE 800000
#define NG 1000
#define DN 92
#define DE 41
#define DH 128

typedef float f32x4 __attribute__((ext_vector_type(4)));
typedef short s16x8 __attribute__((ext_vector_type(8)));

// ws layout (float units):
//  A    [NN][128] f32
//  Pi   [NN][128ch][2] bf16  (f,s interleaved; dst-side)   = NN*128 float-slots
//  Pj   [NN][128ch][2] bf16  (src-side)                    = NN*128 float-slots
//  Wcat [2][512][128] f32    (node-side gate weights, repacked)
//  Wte  [2][256][64]  bf16   (edge-side gate weights, frag layout, K padded)
//  pooled [NG][128] f32
#define OFF_A    0
#define OFF_PI   ((size_t)NN * DH)
#define OFF_PJ   (OFF_PI + (size_t)NN * DH)
#define OFF_WCAT (OFF_PJ + (size_t)NN * DH)
#define OFF_WTE  (OFF_WCAT + (size_t)2 * 512 * 128)
#define OFF_POOL (OFF_WTE + (size_t)2 * 256 * 64 / 2)

__device__ __forceinline__ float leaky(float x) { return x > 0.f ? x : 0.01f * x; }
__device__ __forceinline__ ushort f2bf(float x) {
    uint u = __float_as_uint(x);
    return (ushort)((u + 0x7fffu + ((u >> 16) & 1u)) >> 16);
}
__device__ __forceinline__ float bflo(uint u) { return __uint_as_float(u << 16); }
__device__ __forceinline__ float bfhi(uint u) { return __uint_as_float(u & 0xffff0000u); }

// ---------------- K1: A = leaky_relu(x @ W_node^T + b_node) ----------------
__global__ __launch_bounds__(128) void k_node_embed(const float* __restrict__ x,
        const float* __restrict__ Wn, const float* __restrict__ bn,
        float* __restrict__ A) {
    __shared__ __align__(16) float xs[16 * DN];
    const int n0 = blockIdx.x * 16;
    const int t = threadIdx.x;
    const float4* xg = (const float4*)(x + (size_t)n0 * DN);
    float4* xs4 = (float4*)xs;
    for (int i = t; i < 16 * DN / 4; i += 128) xs4[i] = xg[i];
    __syncthreads();
    const int o = t;
    float acc[16];
#pragma unroll
    for (int n = 0; n < 16; n++) acc[n] = 0.f;
    const float4* Wr = (const float4*)(Wn + (size_t)o * DN);
    for (int kk = 0; kk < DN / 4; kk++) {
        float4 w = Wr[kk];
#pragma unroll
        for (int n = 0; n < 16; n++) {
            float4 a = ((const float4*)(xs + n * DN))[kk];
            acc[n] = fmaf(w.x, a.x, acc[n]);
            acc[n] = fmaf(w.y, a.y, acc[n]);
            acc[n] = fmaf(w.z, a.z, acc[n]);
            acc[n] = fmaf(w.w, a.w, acc[n]);
        }
    }
    float b = bn[o];
#pragma unroll
    for (int n = 0; n < 16; n++)
        A[(size_t)(n0 + n) * DH + o] = leaky(acc[n] + b);
}

// ------- pack Wcat[l][cb*128+o][k] = W{f,s}_l[o][(cb&1)*128 + k] (node side) -------
__global__ __launch_bounds__(128) void k_pack_wcat(const float* __restrict__ Wf1,
        const float* __restrict__ Ws1, const float* __restrict__ Wf2,
        const float* __restrict__ Ws2, float* __restrict__ Wcat) {
    int b = blockIdx.x;              // 0..1023 = layer*512 + row
    int l = b >> 9, row = b & 511;
    int cb = row >> 7, o = row & 127;
    const float* src;
    if (l == 0) src = (cb < 2) ? Wf1 : Ws1;
    else        src = (cb < 2) ? Wf2 : Ws2;
    int koff = (cb & 1) * 128;
    Wcat[(size_t)b * 128 + threadIdx.x] = src[(size_t)o * 297 + koff + threadIdx.x];
}

// ------- pack Wte[l][n][k] bf16: n = c*2+g, k in [0,64) padded from 41 -------
__global__ __launch_bounds__(64) void k_pack_wte(const float* __restrict__ Wf1,
        const float* __restrict__ Ws1, const float* __restrict__ Wf2,
        const float* __restrict__ Ws2, ushort* __restrict__ Wte) {
    int n = blockIdx.x, layer = blockIdx.y, k = threadIdx.x;
    int c = n >> 1, g = n & 1;
    const float* W = layer ? (g ? Ws2 : Wf2) : (g ? Ws1 : Wf1);
    float v = (k < DE) ? W[(size_t)c * 297 + 256 + k] : 0.f;
    Wte[((size_t)(layer * 256 + n)) * 64 + k] = f2bf(v);
}

// ------- Pi/Pj = A @ Wcat^T, written bf16 (f,s)-interleaved; bias in fi/si -------
__global__ __launch_bounds__(256) void k_gemm_P(const float* __restrict__ A,
        const float* __restrict__ Wcat, const float* __restrict__ bf,
        const float* __restrict__ bs, ushort* __restrict__ Pi,
        ushort* __restrict__ Pj) {
    __shared__ __align__(16) float As[64 * 128];
    const int n0 = blockIdx.x * 64;
    const int t = threadIdx.x;
    const float4* Ag = (const float4*)A + (size_t)n0 * 32;
    float4* As4 = (float4*)As;
    for (int i = t; i < 2048; i += 256) {
        int node = n0 + (i >> 5);
        As4[i] = (node < NN) ? Ag[i] : make_float4(0.f, 0.f, 0.f, 0.f);
    }
    __syncthreads();
    const int c = t & 127, nh = t >> 7, cb = blockIdx.y;
    const float4* Wr = (const float4*)(Wcat + ((size_t)cb * 128 + c) * 128);
    float acc[32];
#pragma unroll
    for (int n = 0; n < 32; n++) acc[n] = 0.f;
    for (int kk = 0; kk < 4; kk++) {
        float4 w[8];
#pragma unroll
        for (int jj = 0; jj < 8; jj++) w[jj] = Wr[kk * 8 + jj];
#pragma unroll
        for (int n = 0; n < 32; n++) {
            const float4* Arow = (const float4*)(As + (nh * 32 + n) * 128) + kk * 8;
#pragma unroll
            for (int jj = 0; jj < 8; jj++) {
                float4 a = Arow[jj];
                acc[n] = fmaf(w[jj].x, a.x, acc[n]);
                acc[n] = fmaf(w[jj].y, a.y, acc[n]);
                acc[n] = fmaf(w[jj].z, a.z, acc[n]);
                acc[n] = fmaf(w[jj].w, a.w, acc[n]);
            }
        }
    }
    float bias = 0.f;
    if (cb == 0) bias = bf[c];
    else if (cb == 2) bias = bs[c];
    // cb: 0->fi(Pi,sel0) 1->fj(Pj,sel0) 2->si(Pi,sel1) 3->sj(Pj,sel1)
    ushort* dst = (cb & 1) ? Pj : Pi;
    const int sel = cb >> 1;
#pragma unroll
    for (int n = 0; n < 32; n++) {
        int node = n0 + nh * 32 + n;
        if (node < NN) dst[(size_t)node * 256 + c * 2 + sel] = f2bf(acc[n] + bias);
    }
}

// ------- fused edge kernel: MFMA edge-gate matvec (E in LDS) + gating + atomic agg -------
__global__ __launch_bounds__(256) void k_edge(const ushort* __restrict__ Pi,
        const ushort* __restrict__ Pj, const int* __restrict__ ei,
        const float* __restrict__ ea, const ushort* __restrict__ Wte,
        float* __restrict__ A) {
    __shared__ ushort Elds[64 * 264];   // [64 edges][256 n + 8 pad] bf16
    const int t = threadIdx.x, w = t >> 6, l = t & 63;
    const int e0 = blockIdx.x * 64;
    const int m16 = l & 15, g = l >> 4;

    // ---- phase 1: E = ea_bf16 @ Wte  (M=64 edges, N=256, K=64 padded) ----
    // B frags: lane holds Wte[n0 + m16][ks*32 + g*8 + j], j=0..7
    s16x8 bt[4][2];
#pragma unroll
    for (int nt = 0; nt < 4; nt++)
#pragma unroll
        for (int ks = 0; ks < 2; ks++)
            bt[nt][ks] = *(const s16x8*)(Wte + ((size_t)(w * 64 + nt * 16 + m16)) * 64 + ks * 32 + g * 8);

    // A frags: lane holds ea_bf16[e0 + mt*16 + m16][ks*32 + g*8 + j]
    s16x8 at[4][2];
#pragma unroll
    for (int mt = 0; mt < 4; mt++) {
        const float* row = ea + (size_t)(e0 + mt * 16 + m16) * DE;
        float v[8];
#pragma unroll
        for (int j = 0; j < 8; j++) v[j] = row[g * 8 + j];          // k = g*8+j <= 31 < 41
        s16x8 a0;
#pragma unroll
        for (int j = 0; j < 8; j++) a0[j] = (short)f2bf(v[j]);
        at[mt][0] = a0;
        float v1[8];
#pragma unroll
        for (int j = 0; j < 8; j++) v1[j] = 0.f;
        if (g == 0) {
#pragma unroll
            for (int j = 0; j < 8; j++) v1[j] = row[32 + j];        // 32..39
        } else if (g == 1) {
            v1[0] = row[40];
        }
        s16x8 a1;
#pragma unroll
        for (int j = 0; j < 8; j++) a1[j] = (short)f2bf(v1[j]);
        at[mt][1] = a1;
    }

    f32x4 acc[4][4];
#pragma unroll
    for (int mt = 0; mt < 4; mt++)
#pragma unroll
        for (int nt = 0; nt < 4; nt++)
            acc[mt][nt] = (f32x4){0.f, 0.f, 0.f, 0.f};
#pragma unroll
    for (int ks = 0; ks < 2; ks++)
#pragma unroll
        for (int mt = 0; mt < 4; mt++)
#pragma unroll
            for (int nt = 0; nt < 4; nt++)
                acc[mt][nt] = __builtin_amdgcn_mfma_f32_16x16x32_bf16(
                    at[mt][ks], bt[nt][ks], acc[mt][nt], 0, 0, 0);

    // write E to LDS: D layout col = lane&15 (n), row = (lane>>4)*4 + reg (m)
#pragma unroll
    for (int mt = 0; mt < 4; mt++)
#pragma unroll
        for (int nt = 0; nt < 4; nt++)
#pragma unroll
            for (int r = 0; r < 4; r++)
                Elds[(mt * 16 + g * 4 + r) * 264 + w * 64 + nt * 16 + m16] =
                    f2bf(acc[mt][nt][r]);
    __syncthreads();

    // ---- phase 2: gating + atomic aggregation; wave w handles edges w*16..w*16+15 ----
#pragma unroll 2
    for (int i = 0; i < 16; i++) {
        const int le = w * 16 + i;
        const int e = e0 + le;
        const int src = ei[e], dst = ei[NE + e];
        uint2 pj = *(const uint2*)(Pj + (size_t)src * 256 + 4 * l);
        uint2 pi = *(const uint2*)(Pi + (size_t)dst * 256 + 4 * l);
        uint2 ee = *(const uint2*)(Elds + le * 264 + 4 * l);
        float f0 = bflo(pi.x) + bflo(pj.x) + bflo(ee.x);
        float s0 = bfhi(pi.x) + bfhi(pj.x) + bfhi(ee.x);
        float f1 = bflo(pi.y) + bflo(pj.y) + bflo(ee.y);
        float s1 = bfhi(pi.y) + bfhi(pj.y) + bfhi(ee.y);
        float sg0 = 1.f / (1.f + __expf(-f0));
        float sg1 = 1.f / (1.f + __expf(-f1));
        float sp0 = fmaxf(s0, 0.f) + __logf(1.f + __expf(-fabsf(s0)));
        float sp1 = fmaxf(s1, 0.f) + __logf(1.f + __expf(-fabsf(s1)));
        float m0 = sg0 * sp0, m1 = sg1 * sp1;
        atomicAdd(A + (size_t)dst * DH + 2 * l, m0);
        atomicAdd(A + (size_t)dst * DH + 2 * l + 1, m1);
    }
}

// ---------------- elementwise leaky on A ----------------
__global__ __launch_bounds__(256) void k_act(float* __restrict__ A) {
    int i = blockIdx.x * 256 + threadIdx.x;
    float4* A4 = (float4*)A;
    float4 v = A4[i];
    v.x = leaky(v.x); v.y = leaky(v.y); v.z = leaky(v.z); v.w = leaky(v.w);
    A4[i] = v;
}

// ---------------- final activation + write atom_embs + pooling ----------------
__global__ __launch_bounds__(256) void k_finalize(const float* __restrict__ A,
        const int* __restrict__ batch, float* __restrict__ embs,
        float* __restrict__ pooled) {
    int idx = blockIdx.x * 256 + threadIdx.x;
    int n = idx >> 7, o = idx & 127;
    float v = leaky(A[idx]);
    embs[idx] = v;
    atomicAdd(pooled + (size_t)batch[n] * DH + o, v);
}

// ---------------- head: normalize, W1+leaky, W2 ----------------
__global__ __launch_bounds__(128) void k_head(const float* __restrict__ pooled,
        const float* __restrict__ W1, const float* __restrict__ b1,
        const float* __restrict__ W2, const float* __restrict__ b2,
        float* __restrict__ out) {
    __shared__ __align__(16) float gl[128];
    __shared__ float red[2];
    const int g = blockIdx.x, o = threadIdx.x;
    const int l = o & 63, wid = o >> 6;
    float p = pooled[(size_t)g * DH + o];
    float v = p * p;
#pragma unroll
    for (int off = 32; off >= 1; off >>= 1) v += __shfl_xor(v, off);
    if (l == 0) red[wid] = v;
    __syncthreads();
    float nrm = fmaxf(sqrtf(red[0] + red[1]), 1e-12f);
    float gv = p / nrm;
    gl[o] = gv;
    __syncthreads();
    float gm = b1[o];
    const float4* Wr = (const float4*)(W1 + (size_t)o * DH);
    const float4* gl4 = (const float4*)gl;
    for (int kk = 0; kk < 32; kk++) {
        float4 w = Wr[kk]; float4 a = gl4[kk];
        gm = fmaf(w.x, a.x, gm); gm = fmaf(w.y, a.y, gm);
        gm = fmaf(w.z, a.z, gm); gm = fmaf(w.w, a.w, gm);
    }
    gm = leaky(gm);
    float c = gm * W2[o];
#pragma unroll
    for (int off = 32; off >= 1; off >>= 1) c += __shfl_xor(c, off);
    __syncthreads();
    if (l == 0) red[wid] = c;
    __syncthreads();
    if (o == 0) out[g] = red[0] + red[1] + b2[0];
}

extern "C" void kernel_launch(void* const* d_in, const int* in_sizes, int n_in,
                              void* d_out, int out_size, void* d_ws, size_t ws_size,
                              hipStream_t stream) {
    const float* x    = (const float*)d_in[0];
    const int*   ei   = (const int*)d_in[1];
    const float* ea   = (const float*)d_in[2];
    const int*   batch= (const int*)d_in[3];
    const float* Wn   = (const float*)d_in[4];
    const float* bn   = (const float*)d_in[5];
    const float* Wf1  = (const float*)d_in[6];
    const float* bf1  = (const float*)d_in[7];
    const float* Ws1  = (const float*)d_in[8];
    const float* bs1  = (const float*)d_in[9];
    const float* Wf2  = (const float*)d_in[10];
    const float* bf2  = (const float*)d_in[11];
    const float* Ws2  = (const float*)d_in[12];
    const float* bs2  = (const float*)d_in[13];
    const float* W1   = (const float*)d_in[14];
    const float* b1   = (const float*)d_in[15];
    const float* W2   = (const float*)d_in[16];
    const float* b2   = (const float*)d_in[17];

    float* ws     = (float*)d_ws;
    float*  A     = ws + OFF_A;
    ushort* Pi    = (ushort*)(ws + OFF_PI);
    ushort* Pj    = (ushort*)(ws + OFF_PJ);
    float*  Wcat  = ws + OFF_WCAT;
    ushort* Wte   = (ushort*)(ws + OFF_WTE);
    float*  pooled= ws + OFF_POOL;
    float* out    = (float*)d_out;
    float* embs   = out + NG;

    hipMemsetAsync(pooled, 0, (size_t)NG * DH * sizeof(float), stream);
    k_pack_wcat<<<1024, 128, 0, stream>>>(Wf1, Ws1, Wf2, Ws2, Wcat);
    k_pack_wte<<<dim3(256, 2), 64, 0, stream>>>(Wf1, Ws1, Wf2, Ws2, Wte);
    k_node_embed<<<NN / 16, 128, 0, stream>>>(x, Wn, bn, A);

    // layer 1
    k_gemm_P<<<dim3(782, 4), 256, 0, stream>>>(A, Wcat, bf1, bs1, Pi, Pj);
    k_edge<<<NE / 64, 256, 0, stream>>>(Pi, Pj, ei, ea, Wte, A);
    k_act<<<(NN * DH / 4) / 256, 256, 0, stream>>>(A);

    // layer 2
    k_gemm_P<<<dim3(782, 4), 256, 0, stream>>>(A, Wcat + (size_t)512 * 128, bf2, bs2, Pi, Pj);
    k_edge<<<NE / 64, 256, 0, stream>>>(Pi, Pj, ei, ea, Wte + (size_t)256 * 64, A);

    k_finalize<<<NN * DH / 256, 256, 0, stream>>>(A, batch, embs, pooled);
    k_head<<<NG, 128, 0, stream>>>(pooled, W1, b1, W2, b2, out);
}

// Round 3
// 1138.526 us; speedup vs baseline: 1.7084x; 1.6448x over previous
//
#include <hip/hip_runtime.h>
#include <math.h>

#define NN 50000
#define NE 800000
#define NG 1000
#define DN 92
#define DE 41
#define DH 128

typedef float f32x4 __attribute__((ext_vector_type(4)));
typedef short s16x8 __attribute__((ext_vector_type(8)));

// ws layout (float units):
//  A    [NN][128] f32
//  Pi   [NN][128ch][2] bf16  (f,s interleaved; dst-side)   = NN*128 float-slots
//  Pj   [NN][128ch][2] bf16  (src-side)                    = NN*128 float-slots
//  Wcat [2][512][128] f32    (node-side gate weights, repacked)
//  Wte  [2][256][64]  bf16   (edge-side gate weights, frag layout, K padded)
//  pooled [NG][128] f32
#define OFF_A    0
#define OFF_PI   ((size_t)NN * DH)
#define OFF_PJ   (OFF_PI + (size_t)NN * DH)
#define OFF_WCAT (OFF_PJ + (size_t)NN * DH)
#define OFF_WTE  (OFF_WCAT + (size_t)2 * 512 * 128)
#define OFF_POOL (OFF_WTE + (size_t)2 * 256 * 64 / 2)

__device__ __forceinline__ float leaky(float x) { return x > 0.f ? x : 0.01f * x; }
__device__ __forceinline__ ushort f2bf(float x) {
    uint u = __float_as_uint(x);
    return (ushort)((u + 0x7fffu + ((u >> 16) & 1u)) >> 16);
}
__device__ __forceinline__ float bflo(uint u) { return __uint_as_float(u << 16); }
__device__ __forceinline__ float bfhi(uint u) { return __uint_as_float(u & 0xffff0000u); }

// ---------------- K1: A = leaky_relu(x @ W_node^T + b_node) ----------------
__global__ __launch_bounds__(128) void k_node_embed(const float* __restrict__ x,
        const float* __restrict__ Wn, const float* __restrict__ bn,
        float* __restrict__ A) {
    __shared__ __align__(16) float xs[16 * DN];
    const int n0 = blockIdx.x * 16;
    const int t = threadIdx.x;
    const float4* xg = (const float4*)(x + (size_t)n0 * DN);
    float4* xs4 = (float4*)xs;
    for (int i = t; i < 16 * DN / 4; i += 128) xs4[i] = xg[i];
    __syncthreads();
    const int o = t;
    float acc[16];
#pragma unroll
    for (int n = 0; n < 16; n++) acc[n] = 0.f;
    const float4* Wr = (const float4*)(Wn + (size_t)o * DN);
    for (int kk = 0; kk < DN / 4; kk++) {
        float4 w = Wr[kk];
#pragma unroll
        for (int n = 0; n < 16; n++) {
            float4 a = ((const float4*)(xs + n * DN))[kk];
            acc[n] = fmaf(w.x, a.x, acc[n]);
            acc[n] = fmaf(w.y, a.y, acc[n]);
            acc[n] = fmaf(w.z, a.z, acc[n]);
            acc[n] = fmaf(w.w, a.w, acc[n]);
        }
    }
    float b = bn[o];
#pragma unroll
    for (int n = 0; n < 16; n++)
        A[(size_t)(n0 + n) * DH + o] = leaky(acc[n] + b);
}

// ------- pack Wcat[l][cb*128+o][k] = W{f,s}_l[o][(cb&1)*128 + k] (node side) -------
__global__ __launch_bounds__(128) void k_pack_wcat(const float* __restrict__ Wf1,
        const float* __restrict__ Ws1, const float* __restrict__ Wf2,
        const float* __restrict__ Ws2, float* __restrict__ Wcat) {
    int b = blockIdx.x;              // 0..1023 = layer*512 + row
    int l = b >> 9, row = b & 511;
    int cb = row >> 7, o = row & 127;
    const float* src;
    if (l == 0) src = (cb < 2) ? Wf1 : Ws1;
    else        src = (cb < 2) ? Wf2 : Ws2;
    int koff = (cb & 1) * 128;
    Wcat[(size_t)b * 128 + threadIdx.x] = src[(size_t)o * 297 + koff + threadIdx.x];
}

// ------- pack Wte[l][n][k] bf16: n = c*2+g, k in [0,64) padded from 41 -------
__global__ __launch_bounds__(64) void k_pack_wte(const float* __restrict__ Wf1,
        const float* __restrict__ Ws1, const float* __restrict__ Wf2,
        const float* __restrict__ Ws2, ushort* __restrict__ Wte) {
    int n = blockIdx.x, layer = blockIdx.y, k = threadIdx.x;
    int c = n >> 1, g = n & 1;
    const float* W = layer ? (g ? Ws2 : Wf2) : (g ? Ws1 : Wf1);
    float v = (k < DE) ? W[(size_t)c * 297 + 256 + k] : 0.f;
    Wte[((size_t)(layer * 256 + n)) * 64 + k] = f2bf(v);
}

// ------- Pi/Pj = A @ Wcat^T, written bf16 (f,s)-interleaved; bias in fi/si -------
__global__ __launch_bounds__(256) void k_gemm_P(const float* __restrict__ A,
        const float* __restrict__ Wcat, const float* __restrict__ bf,
        const float* __restrict__ bs, ushort* __restrict__ Pi,
        ushort* __restrict__ Pj) {
    __shared__ __align__(16) float As[64 * 128];
    const int n0 = blockIdx.x * 64;
    const int t = threadIdx.x;
    const float4* Ag = (const float4*)A + (size_t)n0 * 32;
    float4* As4 = (float4*)As;
    for (int i = t; i < 2048; i += 256) {
        int node = n0 + (i >> 5);
        As4[i] = (node < NN) ? Ag[i] : make_float4(0.f, 0.f, 0.f, 0.f);
    }
    __syncthreads();
    const int c = t & 127, nh = t >> 7, cb = blockIdx.y;
    const float4* Wr = (const float4*)(Wcat + ((size_t)cb * 128 + c) * 128);
    float acc[32];
#pragma unroll
    for (int n = 0; n < 32; n++) acc[n] = 0.f;
    for (int kk = 0; kk < 4; kk++) {
        float4 w[8];
#pragma unroll
        for (int jj = 0; jj < 8; jj++) w[jj] = Wr[kk * 8 + jj];
#pragma unroll
        for (int n = 0; n < 32; n++) {
            const float4* Arow = (const float4*)(As + (nh * 32 + n) * 128) + kk * 8;
#pragma unroll
            for (int jj = 0; jj < 8; jj++) {
                float4 a = Arow[jj];
                acc[n] = fmaf(w[jj].x, a.x, acc[n]);
                acc[n] = fmaf(w[jj].y, a.y, acc[n]);
                acc[n] = fmaf(w[jj].z, a.z, acc[n]);
                acc[n] = fmaf(w[jj].w, a.w, acc[n]);
            }
        }
    }
    float bias = 0.f;
    if (cb == 0) bias = bf[c];
    else if (cb == 2) bias = bs[c];
    // cb: 0->fi(Pi,sel0) 1->fj(Pj,sel0) 2->si(Pi,sel1) 3->sj(Pj,sel1)
    ushort* dst = (cb & 1) ? Pj : Pi;
    const int sel = cb >> 1;
#pragma unroll
    for (int n = 0; n < 32; n++) {
        int node = n0 + nh * 32 + n;
        if (node < NN) dst[(size_t)node * 256 + c * 2 + sel] = f2bf(acc[n] + bias);
    }
}

// ------- fused edge kernel: MFMA edge-gate matvec (E in LDS) + gating + atomic agg -------
// 32 edges / block. Phase 2: compute all messages into regs, THEN batch atomics
// (keeps gather waits out of the atomic vmcnt shadow). Lane l owns channels l, l+64
// so each atomic instruction writes 256B contiguous (no sector amplification).
__global__ __launch_bounds__(256) void k_edge(const ushort* __restrict__ Pi,
        const ushort* __restrict__ Pj, const int* __restrict__ ei,
        const float* __restrict__ ea, const ushort* __restrict__ Wte,
        float* __restrict__ A) {
    __shared__ ushort Elds[32 * 264];   // [32 edges][256 n + 8 pad] bf16
    const int t = threadIdx.x, w = t >> 6, l = t & 63;
    const int e0 = blockIdx.x * 32;
    const int m16 = l & 15, g = l >> 4;

    // ---- phase 1: E = ea_bf16 @ Wte  (M=32 edges, N=256, K=64 padded) ----
    // B frags: lane holds Wte[n0 + m16][ks*32 + g*8 + j], j=0..7
    s16x8 bt[4][2];
#pragma unroll
    for (int nt = 0; nt < 4; nt++)
#pragma unroll
        for (int ks = 0; ks < 2; ks++)
            bt[nt][ks] = *(const s16x8*)(Wte + ((size_t)(w * 64 + nt * 16 + m16)) * 64 + ks * 32 + g * 8);

    // A frags: lane holds ea_bf16[e0 + mt*16 + m16][ks*32 + g*8 + j]
    s16x8 at[2][2];
#pragma unroll
    for (int mt = 0; mt < 2; mt++) {
        const float* row = ea + (size_t)(e0 + mt * 16 + m16) * DE;
        float v[8];
#pragma unroll
        for (int j = 0; j < 8; j++) v[j] = row[g * 8 + j];          // k = g*8+j <= 31 < 41
        s16x8 a0;
#pragma unroll
        for (int j = 0; j < 8; j++) a0[j] = (short)f2bf(v[j]);
        at[mt][0] = a0;
        float v1[8];
#pragma unroll
        for (int j = 0; j < 8; j++) v1[j] = 0.f;
        if (g == 0) {
#pragma unroll
            for (int j = 0; j < 8; j++) v1[j] = row[32 + j];        // 32..39
        } else if (g == 1) {
            v1[0] = row[40];
        }
        s16x8 a1;
#pragma unroll
        for (int j = 0; j < 8; j++) a1[j] = (short)f2bf(v1[j]);
        at[mt][1] = a1;
    }

    f32x4 acc[2][4];
#pragma unroll
    for (int mt = 0; mt < 2; mt++)
#pragma unroll
        for (int nt = 0; nt < 4; nt++)
            acc[mt][nt] = (f32x4){0.f, 0.f, 0.f, 0.f};
#pragma unroll
    for (int ks = 0; ks < 2; ks++)
#pragma unroll
        for (int mt = 0; mt < 2; mt++)
#pragma unroll
            for (int nt = 0; nt < 4; nt++)
                acc[mt][nt] = __builtin_amdgcn_mfma_f32_16x16x32_bf16(
                    at[mt][ks], bt[nt][ks], acc[mt][nt], 0, 0, 0);

    // write E to LDS: D layout col = lane&15 (n), row = (lane>>4)*4 + reg (m)
#pragma unroll
    for (int mt = 0; mt < 2; mt++)
#pragma unroll
        for (int nt = 0; nt < 4; nt++)
#pragma unroll
            for (int r = 0; r < 4; r++)
                Elds[(mt * 16 + g * 4 + r) * 264 + w * 64 + nt * 16 + m16] =
                    f2bf(acc[mt][nt][r]);
    __syncthreads();

    // ---- phase 2: wave w computes edges w*8..w*8+7 into regs, then commits ----
    const uint* PiU = (const uint*)Pi;   // uint c = (f_c, s_c) bf16 pair
    const uint* PjU = (const uint*)Pj;
    const uint* ElU = (const uint*)Elds; // row stride 132 uints
    const int base = w * 8;
    int dsts[8];
    float msg[8][2];
#pragma unroll
    for (int i = 0; i < 8; i++) {
        const int le = base + i;
        const int e = e0 + le;
        const int src = ei[e], dst = ei[NE + e];
        dsts[i] = dst;
        uint pj0 = PjU[(size_t)src * 128 + l];
        uint pj1 = PjU[(size_t)src * 128 + 64 + l];
        uint pi0 = PiU[(size_t)dst * 128 + l];
        uint pi1 = PiU[(size_t)dst * 128 + 64 + l];
        uint ev0 = ElU[le * 132 + l];
        uint ev1 = ElU[le * 132 + 64 + l];
        float f0 = bflo(pi0) + bflo(pj0) + bflo(ev0);
        float s0 = bfhi(pi0) + bfhi(pj0) + bfhi(ev0);
        float f1 = bflo(pi1) + bflo(pj1) + bflo(ev1);
        float s1 = bfhi(pi1) + bfhi(pj1) + bfhi(ev1);
        float sg0 = 1.f / (1.f + __expf(-f0));
        float sg1 = 1.f / (1.f + __expf(-f1));
        float sp0 = fmaxf(s0, 0.f) + __logf(1.f + __expf(-fabsf(s0)));
        float sp1 = fmaxf(s1, 0.f) + __logf(1.f + __expf(-fabsf(s1)));
        msg[i][0] = sg0 * sp0;
        msg[i][1] = sg1 * sp1;
    }
#pragma unroll
    for (int i = 0; i < 8; i++) {
        atomicAdd(A + (size_t)dsts[i] * DH + l, msg[i][0]);
        atomicAdd(A + (size_t)dsts[i] * DH + 64 + l, msg[i][1]);
    }
}

// ---------------- elementwise leaky on A ----------------
__global__ __launch_bounds__(256) void k_act(float* __restrict__ A) {
    int i = blockIdx.x * 256 + threadIdx.x;
    float4* A4 = (float4*)A;
    float4 v = A4[i];
    v.x = leaky(v.x); v.y = leaky(v.y); v.z = leaky(v.z); v.w = leaky(v.w);
    A4[i] = v;
}

// ---------------- final activation + write atom_embs + pooling ----------------
__global__ __launch_bounds__(256) void k_finalize(const float* __restrict__ A,
        const int* __restrict__ batch, float* __restrict__ embs,
        float* __restrict__ pooled) {
    int idx = blockIdx.x * 256 + threadIdx.x;
    int n = idx >> 7, o = idx & 127;
    float v = leaky(A[idx]);
    embs[idx] = v;
    atomicAdd(pooled + (size_t)batch[n] * DH + o, v);
}

// ---------------- head: normalize, W1+leaky, W2 ----------------
__global__ __launch_bounds__(128) void k_head(const float* __restrict__ pooled,
        const float* __restrict__ W1, const float* __restrict__ b1,
        const float* __restrict__ W2, const float* __restrict__ b2,
        float* __restrict__ out) {
    __shared__ __align__(16) float gl[128];
    __shared__ float red[2];
    const int g = blockIdx.x, o = threadIdx.x;
    const int l = o & 63, wid = o >> 6;
    float p = pooled[(size_t)g * DH + o];
    float v = p * p;
#pragma unroll
    for (int off = 32; off >= 1; off >>= 1) v += __shfl_xor(v, off);
    if (l == 0) red[wid] = v;
    __syncthreads();
    float nrm = fmaxf(sqrtf(red[0] + red[1]), 1e-12f);
    float gv = p / nrm;
    gl[o] = gv;
    __syncthreads();
    float gm = b1[o];
    const float4* Wr = (const float4*)(W1 + (size_t)o * DH);
    const float4* gl4 = (const float4*)gl;
    for (int kk = 0; kk < 32; kk++) {
        float4 w = Wr[kk]; float4 a = gl4[kk];
        gm = fmaf(w.x, a.x, gm); gm = fmaf(w.y, a.y, gm);
        gm = fmaf(w.z, a.z, gm); gm = fmaf(w.w, a.w, gm);
    }
    gm = leaky(gm);
    float c = gm * W2[o];
#pragma unroll
    for (int off = 32; off >= 1; off >>= 1) c += __shfl_xor(c, off);
    __syncthreads();
    if (l == 0) red[wid] = c;
    __syncthreads();
    if (o == 0) out[g] = red[0] + red[1] + b2[0];
}

extern "C" void kernel_launch(void* const* d_in, const int* in_sizes, int n_in,
                              void* d_out, int out_size, void* d_ws, size_t ws_size,
                              hipStream_t stream) {
    const float* x    = (const float*)d_in[0];
    const int*   ei   = (const int*)d_in[1];
    const float* ea   = (const float*)d_in[2];
    const int*   batch= (const int*)d_in[3];
    const float* Wn   = (const float*)d_in[4];
    const float* bn   = (const float*)d_in[5];
    const float* Wf1  = (const float*)d_in[6];
    const float* bf1  = (const float*)d_in[7];
    const float* Ws1  = (const float*)d_in[8];
    const float* bs1  = (const float*)d_in[9];
    const float* Wf2  = (const float*)d_in[10];
    const float* bf2  = (const float*)d_in[11];
    const float* Ws2  = (const float*)d_in[12];
    const float* bs2  = (const float*)d_in[13];
    const float* W1   = (const float*)d_in[14];
    const float* b1   = (const float*)d_in[15];
    const float* W2   = (const float*)d_in[16];
    const float* b2   = (const float*)d_in[17];

    float* ws     = (float*)d_ws;
    float*  A     = ws + OFF_A;
    ushort* Pi    = (ushort*)(ws + OFF_PI);
    ushort* Pj    = (ushort*)(ws + OFF_PJ);
    float*  Wcat  = ws + OFF_WCAT;
    ushort* Wte   = (ushort*)(ws + OFF_WTE);
    float*  pooled= ws + OFF_POOL;
    float* out    = (float*)d_out;
    float* embs   = out + NG;

    hipMemsetAsync(pooled, 0, (size_t)NG * DH * sizeof(float), stream);
    k_pack_wcat<<<1024, 128, 0, stream>>>(Wf1, Ws1, Wf2, Ws2, Wcat);
    k_pack_wte<<<dim3(256, 2), 64, 0, stream>>>(Wf1, Ws1, Wf2, Ws2, Wte);
    k_node_embed<<<NN / 16, 128, 0, stream>>>(x, Wn, bn, A);

    // layer 1
    k_gemm_P<<<dim3(782, 4), 256, 0, stream>>>(A, Wcat, bf1, bs1, Pi, Pj);
    k_edge<<<NE / 32, 256, 0, stream>>>(Pi, Pj, ei, ea, Wte, A);
    k_act<<<(NN * DH / 4) / 256, 256, 0, stream>>>(A);

    // layer 2
    k_gemm_P<<<dim3(782, 4), 256, 0, stream>>>(A, Wcat + (size_t)512 * 128, bf2, bs2, Pi, Pj);
    k_edge<<<NE / 32, 256, 0, stream>>>(Pi, Pj, ei, ea, Wte + (size_t)256 * 64, A);

    k_finalize<<<NN * DH / 256, 256, 0, stream>>>(A, batch, embs, pooled);
    k_head<<<NG, 128, 0, stream>>>(pooled, W1, b1, W2, b2, out);
}

// Round 4
// 734.961 us; speedup vs baseline: 2.6465x; 1.5491x over previous
//
#include <hip/hip_runtime.h>
#include <math.h>

#define NN 50000
#define NE 800000
#define NG 1000
#define DN 92
#define DE 41
#define DH 128

typedef float f32x4 __attribute__((ext_vector_type(4)));
typedef short s16x8 __attribute__((ext_vector_type(8)));

// ws layout (float units):
//  A      [NN][128] f32         node state
//  Abf    [NN][128] bf16        bf16 mirror of A (gemm input)
//  Pi     [NN][128c][2] bf16    dst-side gate proj (f,s interleaved)
//  Pj     [NN][128c][2] bf16    src-side
//  Wcatb  [2][512][128] bf16    node-side gate weights
//  Wte    [2][256][64] bf16     edge-side gate weights (frag layout)
//  pooled [NG][128] f32
//  cnt/cur[NN] int              sort scratch
//  se     [NE] uint2            sorted (src, eid)
//  sdst   [NE] int              sorted dst
#define OFF_A     ((size_t)0)
#define OFF_ABF   ((size_t)6400000)
#define OFF_PI    ((size_t)9600000)
#define OFF_PJ    ((size_t)16000000)
#define OFF_WCATB ((size_t)22400000)
#define OFF_WTE   ((size_t)22465536)
#define OFF_POOL  ((size_t)22481920)
#define OFF_CNT   ((size_t)22609920)
#define OFF_CUR   ((size_t)22659920)
#define OFF_SE    ((size_t)22709920)
#define OFF_SDST  ((size_t)24309920)

__device__ __forceinline__ float leaky(float x) { return x > 0.f ? x : 0.01f * x; }
__device__ __forceinline__ ushort f2bf(float x) {
    uint u = __float_as_uint(x);
    return (ushort)((u + 0x7fffu + ((u >> 16) & 1u)) >> 16);
}
__device__ __forceinline__ float bflo(uint u) { return __uint_as_float(u << 16); }
__device__ __forceinline__ float bfhi(uint u) { return __uint_as_float(u & 0xffff0000u); }

// ---------------- K1: A = leaky_relu(x @ W_node^T + b_node); also Abf ----------------
__global__ __launch_bounds__(128) void k_node_embed(const float* __restrict__ x,
        const float* __restrict__ Wn, const float* __restrict__ bn,
        float* __restrict__ A, ushort* __restrict__ Abf) {
    __shared__ __align__(16) float xs[16 * DN];
    const int n0 = blockIdx.x * 16;
    const int t = threadIdx.x;
    const float4* xg = (const float4*)(x + (size_t)n0 * DN);
    float4* xs4 = (float4*)xs;
    for (int i = t; i < 16 * DN / 4; i += 128) xs4[i] = xg[i];
    __syncthreads();
    const int o = t;
    float acc[16];
#pragma unroll
    for (int n = 0; n < 16; n++) acc[n] = 0.f;
    const float4* Wr = (const float4*)(Wn + (size_t)o * DN);
    for (int kk = 0; kk < DN / 4; kk++) {
        float4 w = Wr[kk];
#pragma unroll
        for (int n = 0; n < 16; n++) {
            float4 a = ((const float4*)(xs + n * DN))[kk];
            acc[n] = fmaf(w.x, a.x, acc[n]);
            acc[n] = fmaf(w.y, a.y, acc[n]);
            acc[n] = fmaf(w.z, a.z, acc[n]);
            acc[n] = fmaf(w.w, a.w, acc[n]);
        }
    }
    float b = bn[o];
#pragma unroll
    for (int n = 0; n < 16; n++) {
        float v = leaky(acc[n] + b);
        A[(size_t)(n0 + n) * DH + o] = v;
        Abf[(size_t)(n0 + n) * DH + o] = f2bf(v);
    }
}

// ------- pack Wcatb[l][cb*128+o][k] = bf16(W{f,s}_l[o][(cb&1)*128 + k]) -------
__global__ __launch_bounds__(128) void k_pack_wcatb(const float* __restrict__ Wf1,
        const float* __restrict__ Ws1, const float* __restrict__ Wf2,
        const float* __restrict__ Ws2, ushort* __restrict__ Wcatb) {
    int b = blockIdx.x;              // 0..1023 = layer*512 + row
    int l = b >> 9, row = b & 511;
    int cb = row >> 7, o = row & 127;
    const float* src;
    if (l == 0) src = (cb < 2) ? Wf1 : Ws1;
    else        src = (cb < 2) ? Wf2 : Ws2;
    int koff = (cb & 1) * 128;
    Wcatb[(size_t)b * 128 + threadIdx.x] = f2bf(src[(size_t)o * 297 + koff + threadIdx.x]);
}

// ------- pack Wte[l][n][k] bf16: n = c*2+g, k in [0,64) padded from 41 -------
__global__ __launch_bounds__(64) void k_pack_wte(const float* __restrict__ Wf1,
        const float* __restrict__ Ws1, const float* __restrict__ Wf2,
        const float* __restrict__ Ws2, ushort* __restrict__ Wte) {
    int n = blockIdx.x, layer = blockIdx.y, k = threadIdx.x;
    int c = n >> 1, g = n & 1;
    const float* W = layer ? (g ? Ws2 : Wf2) : (g ? Ws1 : Wf1);
    float v = (k < DE) ? W[(size_t)c * 297 + 256 + k] : 0.f;
    Wte[((size_t)(layer * 256 + n)) * 64 + k] = f2bf(v);
}

// ---------------- edge sort by dst: histogram / scan / scatter ----------------
__global__ __launch_bounds__(256) void k_hist(const int* __restrict__ ei,
        int* __restrict__ cnt) {
    int e = blockIdx.x * 256 + threadIdx.x;
    atomicAdd(&cnt[ei[NE + e]], 1);
}

__global__ __launch_bounds__(1024) void k_scan(const int* __restrict__ cnt,
        int* __restrict__ cur) {
    __shared__ int part[1024];
    const int t = threadIdx.x;
    const int lo = t * 49, hi = min(lo + 49, NN);
    int s = 0;
    for (int i = lo; i < hi; i++) s += cnt[i];
    part[t] = s;
    __syncthreads();
    for (int off = 1; off < 1024; off <<= 1) {
        int u = (t >= off) ? part[t - off] : 0;
        __syncthreads();
        part[t] += u;
        __syncthreads();
    }
    int run = part[t] - s;   // exclusive prefix
    for (int i = lo; i < hi; i++) { int c = cnt[i]; cur[i] = run; run += c; }
}

__global__ __launch_bounds__(256) void k_scatter(const int* __restrict__ ei,
        int* __restrict__ cur, uint2* __restrict__ se, int* __restrict__ sdst) {
    int e = blockIdx.x * 256 + threadIdx.x;
    int src = ei[e], dst = ei[NE + e];
    int pos = atomicAdd(&cur[dst], 1);
    se[pos] = make_uint2((uint)src, (uint)e);
    sdst[pos] = dst;
}

// ------- P = Abf @ Wcatb^T via MFMA; block = 32 nodes x N512 (wave w = cb w) -------
__global__ __launch_bounds__(256) void k_gemm_P2(const ushort* __restrict__ Abf,
        const ushort* __restrict__ Wcatb, const float* __restrict__ bf,
        const float* __restrict__ bs, ushort* __restrict__ Pi,
        ushort* __restrict__ Pj) {
    __shared__ ushort Alds[32 * 136];
    __shared__ ushort OTi[32 * 264];
    __shared__ ushort OTj[32 * 264];
    const int n0 = blockIdx.x * 32;
    const int t = threadIdx.x;
    const int cb = t >> 6, l = t & 63, m16 = l & 15, g = l >> 4;

    // stage A tile (32 nodes x 128 k, bf16), padded stride 136
    const uint4* Ag = (const uint4*)Abf;
#pragma unroll
    for (int p = 0; p < 2; p++) {
        int row = (t >> 4) + p * 16;
        int node = n0 + row;
        uint4 v = make_uint4(0u, 0u, 0u, 0u);
        if (node < NN) v = Ag[(size_t)node * 16 + (t & 15)];
        *(uint4*)(Alds + row * 136 + (t & 15) * 8) = v;
    }
    __syncthreads();

    const ushort* Bw = Wcatb + (size_t)cb * 128 * 128;
    f32x4 acc[2][8];
#pragma unroll
    for (int mt = 0; mt < 2; mt++)
#pragma unroll
        for (int nt = 0; nt < 8; nt++) acc[mt][nt] = (f32x4){0.f, 0.f, 0.f, 0.f};

    for (int ks = 0; ks < 4; ks++) {
        s16x8 bfr[8];
#pragma unroll
        for (int nt = 0; nt < 8; nt++)
            bfr[nt] = *(const s16x8*)(Bw + ((size_t)(nt * 16 + m16)) * 128 + ks * 32 + g * 8);
        s16x8 afr[2];
#pragma unroll
        for (int mt = 0; mt < 2; mt++)
            afr[mt] = *(const s16x8*)(Alds + (mt * 16 + m16) * 136 + ks * 32 + g * 8);
#pragma unroll
        for (int mt = 0; mt < 2; mt++)
#pragma unroll
            for (int nt = 0; nt < 8; nt++)
                acc[mt][nt] = __builtin_amdgcn_mfma_f32_16x16x32_bf16(
                    afr[mt], bfr[nt], acc[mt][nt], 0, 0, 0);
    }

    // epilogue: bias, bf16, interleave into OT, coalesced global write
    float bias[8];
#pragma unroll
    for (int nt = 0; nt < 8; nt++) bias[nt] = 0.f;
    if (cb == 0) {
#pragma unroll
        for (int nt = 0; nt < 8; nt++) bias[nt] = bf[nt * 16 + m16];
    } else if (cb == 2) {
#pragma unroll
        for (int nt = 0; nt < 8; nt++) bias[nt] = bs[nt * 16 + m16];
    }
    ushort* OT = (cb & 1) ? OTj : OTi;
    const int sel = cb >> 1;
#pragma unroll
    for (int mt = 0; mt < 2; mt++)
#pragma unroll
        for (int nt = 0; nt < 8; nt++)
#pragma unroll
            for (int r = 0; r < 4; r++)
                OT[(mt * 16 + g * 4 + r) * 264 + (nt * 16 + m16) * 2 + sel] =
                    f2bf(acc[mt][nt][r] + bias[nt]);
    __syncthreads();
#pragma unroll
    for (int p = 0; p < 4; p++) {
        int idx = t + p * 256;
        int row = idx >> 5, col8 = idx & 31;
        int node = n0 + row;
        if (node < NN) {
            *(uint4*)(Pi + (size_t)node * 256 + col8 * 8) = *(const uint4*)(OTi + row * 264 + col8 * 8);
            *(uint4*)(Pj + (size_t)node * 256 + col8 * 8) = *(const uint4*)(OTj + row * 264 + col8 * 8);
        }
    }
}

// ------- edge kernel on dst-sorted slots: MFMA edge matvec + gating + run-batched atomics -------
__global__ __launch_bounds__(256) void k_edge(const ushort* __restrict__ Pi,
        const ushort* __restrict__ Pj, const uint2* __restrict__ se,
        const int* __restrict__ sdst, const float* __restrict__ ea,
        const ushort* __restrict__ Wte, float* __restrict__ A) {
    __shared__ ushort Elds[32 * 264];
    const int t = threadIdx.x, w = t >> 6, l = t & 63;
    const int e0 = blockIdx.x * 32;
    const int m16 = l & 15, g = l >> 4;

    // ---- phase 1: E = ea_bf16 @ Wte (M=32 sorted edges via eid, N=256, K=64) ----
    s16x8 bt[4][2];
#pragma unroll
    for (int nt = 0; nt < 4; nt++)
#pragma unroll
        for (int ks = 0; ks < 2; ks++)
            bt[nt][ks] = *(const s16x8*)(Wte + ((size_t)(w * 64 + nt * 16 + m16)) * 64 + ks * 32 + g * 8);

    s16x8 at[2][2];
#pragma unroll
    for (int mt = 0; mt < 2; mt++) {
        uint2 s2 = se[e0 + mt * 16 + m16];
        const float* row = ea + (size_t)s2.y * DE;
        float v[8];
#pragma unroll
        for (int j = 0; j < 8; j++) v[j] = row[g * 8 + j];
        s16x8 a0;
#pragma unroll
        for (int j = 0; j < 8; j++) a0[j] = (short)f2bf(v[j]);
        at[mt][0] = a0;
        float v1[8];
#pragma unroll
        for (int j = 0; j < 8; j++) v1[j] = 0.f;
        if (g == 0) {
#pragma unroll
            for (int j = 0; j < 8; j++) v1[j] = row[32 + j];
        } else if (g == 1) {
            v1[0] = row[40];
        }
        s16x8 a1;
#pragma unroll
        for (int j = 0; j < 8; j++) a1[j] = (short)f2bf(v1[j]);
        at[mt][1] = a1;
    }

    f32x4 acc[2][4];
#pragma unroll
    for (int mt = 0; mt < 2; mt++)
#pragma unroll
        for (int nt = 0; nt < 4; nt++)
            acc[mt][nt] = (f32x4){0.f, 0.f, 0.f, 0.f};
#pragma unroll
    for (int ks = 0; ks < 2; ks++)
#pragma unroll
        for (int mt = 0; mt < 2; mt++)
#pragma unroll
            for (int nt = 0; nt < 4; nt++)
                acc[mt][nt] = __builtin_amdgcn_mfma_f32_16x16x32_bf16(
                    at[mt][ks], bt[nt][ks], acc[mt][nt], 0, 0, 0);

#pragma unroll
    for (int mt = 0; mt < 2; mt++)
#pragma unroll
        for (int nt = 0; nt < 4; nt++)
#pragma unroll
            for (int r = 0; r < 4; r++)
                Elds[(mt * 16 + g * 4 + r) * 264 + w * 64 + nt * 16 + m16] =
                    f2bf(acc[mt][nt][r]);
    __syncthreads();

    // ---- phase 2: wave w -> sorted edges base..base+7; run-detected commit ----
    const uint* PiU = (const uint*)Pi;
    const uint* PjU = (const uint*)Pj;
    const uint* ElU = (const uint*)Elds;
    const int base = e0 + w * 8;
    int dsts[8];
    float msg[8][2];
#pragma unroll
    for (int i = 0; i < 8; i++) {
        const int src = __builtin_amdgcn_readfirstlane((int)se[base + i].x);
        const int dst = __builtin_amdgcn_readfirstlane(sdst[base + i]);
        dsts[i] = dst;
        uint pj0 = PjU[(size_t)src * 128 + l];
        uint pj1 = PjU[(size_t)src * 128 + 64 + l];
        uint pi0 = PiU[(size_t)dst * 128 + l];
        uint pi1 = PiU[(size_t)dst * 128 + 64 + l];
        uint ev0 = ElU[(w * 8 + i) * 132 + l];
        uint ev1 = ElU[(w * 8 + i) * 132 + 64 + l];
        float f0 = bflo(pi0) + bflo(pj0) + bflo(ev0);
        float s0 = bfhi(pi0) + bfhi(pj0) + bfhi(ev0);
        float f1 = bflo(pi1) + bflo(pj1) + bflo(ev1);
        float s1 = bfhi(pi1) + bfhi(pj1) + bfhi(ev1);
        float sg0 = 1.f / (1.f + __expf(-f0));
        float sg1 = 1.f / (1.f + __expf(-f1));
        float sp0 = fmaxf(s0, 0.f) + __logf(1.f + __expf(-fabsf(s0)));
        float sp1 = fmaxf(s1, 0.f) + __logf(1.f + __expf(-fabsf(s1)));
        msg[i][0] = sg0 * sp0;
        msg[i][1] = sg1 * sp1;
    }
    float a0 = msg[0][0], a1 = msg[0][1];
#pragma unroll
    for (int i = 1; i < 8; i++) {
        if (dsts[i] == dsts[i - 1]) {
            a0 += msg[i][0]; a1 += msg[i][1];
        } else {
            atomicAdd(A + (size_t)dsts[i - 1] * DH + l, a0);
            atomicAdd(A + (size_t)dsts[i - 1] * DH + 64 + l, a1);
            a0 = msg[i][0]; a1 = msg[i][1];
        }
    }
    atomicAdd(A + (size_t)dsts[7] * DH + l, a0);
    atomicAdd(A + (size_t)dsts[7] * DH + 64 + l, a1);
}

// ---------------- elementwise leaky on A; refresh Abf ----------------
__global__ __launch_bounds__(256) void k_act(float* __restrict__ A,
        ushort* __restrict__ Abf) {
    int i = blockIdx.x * 256 + threadIdx.x;
    float4* A4 = (float4*)A;
    float4 v = A4[i];
    v.x = leaky(v.x); v.y = leaky(v.y); v.z = leaky(v.z); v.w = leaky(v.w);
    A4[i] = v;
    ((uint2*)Abf)[i] = make_uint2((uint)f2bf(v.x) | ((uint)f2bf(v.y) << 16),
                                  (uint)f2bf(v.z) | ((uint)f2bf(v.w) << 16));
}

// ---------------- final activation + write atom_embs + pooling ----------------
__global__ __launch_bounds__(256) void k_finalize(const float* __restrict__ A,
        const int* __restrict__ batch, float* __restrict__ embs,
        float* __restrict__ pooled) {
    int idx = blockIdx.x * 256 + threadIdx.x;
    int n = idx >> 7, o = idx & 127;
    float v = leaky(A[idx]);
    embs[idx] = v;
    atomicAdd(pooled + (size_t)batch[n] * DH + o, v);
}

// ---------------- head: normalize, W1+leaky, W2 ----------------
__global__ __launch_bounds__(128) void k_head(const float* __restrict__ pooled,
        const float* __restrict__ W1, const float* __restrict__ b1,
        const float* __restrict__ W2, const float* __restrict__ b2,
        float* __restrict__ out) {
    __shared__ __align__(16) float gl[128];
    __shared__ float red[2];
    const int g = blockIdx.x, o = threadIdx.x;
    const int l = o & 63, wid = o >> 6;
    float p = pooled[(size_t)g * DH + o];
    float v = p * p;
#pragma unroll
    for (int off = 32; off >= 1; off >>= 1) v += __shfl_xor(v, off);
    if (l == 0) red[wid] = v;
    __syncthreads();
    float nrm = fmaxf(sqrtf(red[0] + red[1]), 1e-12f);
    float gv = p / nrm;
    gl[o] = gv;
    __syncthreads();
    float gm = b1[o];
    const float4* Wr = (const float4*)(W1 + (size_t)o * DH);
    const float4* gl4 = (const float4*)gl;
    for (int kk = 0; kk < 32; kk++) {
        float4 w = Wr[kk]; float4 a = gl4[kk];
        gm = fmaf(w.x, a.x, gm); gm = fmaf(w.y, a.y, gm);
        gm = fmaf(w.z, a.z, gm); gm = fmaf(w.w, a.w, gm);
    }
    gm = leaky(gm);
    float c = gm * W2[o];
#pragma unroll
    for (int off = 32; off >= 1; off >>= 1) c += __shfl_xor(c, off);
    __syncthreads();
    if (l == 0) red[wid] = c;
    __syncthreads();
    if (o == 0) out[g] = red[0] + red[1] + b2[0];
}

extern "C" void kernel_launch(void* const* d_in, const int* in_sizes, int n_in,
                              void* d_out, int out_size, void* d_ws, size_t ws_size,
                              hipStream_t stream) {
    const float* x    = (const float*)d_in[0];
    const int*   ei   = (const int*)d_in[1];
    const float* ea   = (const float*)d_in[2];
    const int*   batch= (const int*)d_in[3];
    const float* Wn   = (const float*)d_in[4];
    const float* bn   = (const float*)d_in[5];
    const float* Wf1  = (const float*)d_in[6];
    const float* bf1  = (const float*)d_in[7];
    const float* Ws1  = (const float*)d_in[8];
    const float* bs1  = (const float*)d_in[9];
    const float* Wf2  = (const float*)d_in[10];
    const float* bf2  = (const float*)d_in[11];
    const float* Ws2  = (const float*)d_in[12];
    const float* bs2  = (const float*)d_in[13];
    const float* W1   = (const float*)d_in[14];
    const float* b1   = (const float*)d_in[15];
    const float* W2   = (const float*)d_in[16];
    const float* b2   = (const float*)d_in[17];

    float* ws      = (float*)d_ws;
    float*  A      = ws + OFF_A;
    ushort* Abf    = (ushort*)(ws + OFF_ABF);
    ushort* Pi     = (ushort*)(ws + OFF_PI);
    ushort* Pj     = (ushort*)(ws + OFF_PJ);
    ushort* Wcatb  = (ushort*)(ws + OFF_WCATB);
    ushort* Wte    = (ushort*)(ws + OFF_WTE);
    float*  pooled = ws + OFF_POOL;
    int*    cnt    = (int*)(ws + OFF_CNT);
    int*    cur    = (int*)(ws + OFF_CUR);
    uint2*  se     = (uint2*)(ws + OFF_SE);
    int*    sdst   = (int*)(ws + OFF_SDST);
    float* out     = (float*)d_out;
    float* embs    = out + NG;

    hipMemsetAsync(pooled, 0, (size_t)NG * DH * sizeof(float), stream);
    hipMemsetAsync(cnt, 0, (size_t)NN * sizeof(int), stream);
    k_pack_wcatb<<<1024, 128, 0, stream>>>(Wf1, Ws1, Wf2, Ws2, Wcatb);
    k_pack_wte<<<dim3(256, 2), 64, 0, stream>>>(Wf1, Ws1, Wf2, Ws2, Wte);
    k_node_embed<<<NN / 16, 128, 0, stream>>>(x, Wn, bn, A, Abf);

    // sort edges by dst (shared by both layers)
    k_hist<<<NE / 256, 256, 0, stream>>>(ei, cnt);
    k_scan<<<1, 1024, 0, stream>>>(cnt, cur);
    k_scatter<<<NE / 256, 256, 0, stream>>>(ei, cur, se, sdst);

    // layer 1
    k_gemm_P2<<<(NN + 31) / 32, 256, 0, stream>>>(Abf, Wcatb, bf1, bs1, Pi, Pj);
    k_edge<<<NE / 32, 256, 0, stream>>>(Pi, Pj, se, sdst, ea, Wte, A);
    k_act<<<(NN * DH / 4) / 256, 256, 0, stream>>>(A, Abf);

    // layer 2
    k_gemm_P2<<<(NN + 31) / 32, 256, 0, stream>>>(Abf, Wcatb + (size_t)512 * 128, bf2, bs2, Pi, Pj);
    k_edge<<<NE / 32, 256, 0, stream>>>(Pi, Pj, se, sdst, ea, Wte + (size_t)256 * 64, A);

    k_finalize<<<NN * DH / 256, 256, 0, stream>>>(A, batch, embs, pooled);
    k_head<<<NG, 128, 0, stream>>>(pooled, W1, b1, W2, b2, out);
}